// Round 17
// baseline (317.897 us; speedup 1.0000x reference)
//
#include <hip/hip_runtime.h>
#include <stdint.h>

#define D 128
#define CHUNK 6400

typedef __attribute__((ext_vector_type(8))) __bf16 bf16x8;
typedef __attribute__((ext_vector_type(4))) __bf16 bf16x4;
typedef __attribute__((ext_vector_type(4))) float f32x4;

// ---------------------------------------------------------------------------
// edge_index dtype detection (int64 per reference vs int32 from x64-disabled JAX)
__global__ void detect_idx(const void* ei, int* flag, int n_nodes) {
    if (blockIdx.x == 0 && threadIdx.x == 0) {
        const long long* p = (const long long*)ei;
        int is64 = 1;
        for (int i = 0; i < 64; ++i) {
            long long v = p[i];
            if (v < 0 || v >= (long long)n_nodes) { is64 = 0; break; }
        }
        *flag = is64;
    }
}

// ---------------------------------------------------------------------------
// one pass over edge_index: packed edge word (src<<9 | dst&511), bucket byte,
// bucket histogram (LDS -> global).
__global__ __launch_bounds__(256) void convert_pack(
        const void* __restrict__ ei, const int* __restrict__ flag,
        unsigned int* __restrict__ eword, unsigned char* __restrict__ gb,
        int* __restrict__ bcnt, int nE) {
    __shared__ int l[256];
    l[threadIdx.x] = 0;
    __syncthreads();
    bool is64 = *flag != 0;
    int stride = gridDim.x * 256;
    for (int e = blockIdx.x * 256 + threadIdx.x; e < nE; e += stride) {
        int s, d;
        if (is64) {
            const long long* p = (const long long*)ei;
            s = (int)p[e];
            d = (int)p[(size_t)nE + e];
        } else {
            const int* p = (const int*)ei;
            s = p[e];
            d = p[nE + e];
        }
        eword[e] = ((unsigned)s << 9) | (unsigned)(d & 511);
        gb[e] = (unsigned char)(d >> 9);
        atomicAdd(&l[d >> 9], 1);
    }
    __syncthreads();
    int v = l[threadIdx.x];
    if (v) atomicAdd(&bcnt[threadIdx.x], v);
}

__global__ void bucket_scan(const int* __restrict__ bcnt, int* __restrict__ bstart,
                            int* __restrict__ bcur, int G, int nE,
                            int* __restrict__ offsets, int n) {
    __shared__ int s[256];
    int t = threadIdx.x;
    int v = (t < G) ? bcnt[t] : 0;
    s[t] = v;
    __syncthreads();
    for (int off = 1; off < 256; off <<= 1) {
        int u = 0;
        if (t >= off) u = s[t - off];
        __syncthreads();
        if (t >= off) s[t] += u;
        __syncthreads();
    }
    if (t < G) { int ex = s[t] - v; bstart[t] = ex; bcur[t] = ex; }
    if (t == 0) offsets[n] = nE;
}

__global__ __launch_bounds__(256) void bucket_fill2(
        const unsigned int* __restrict__ eword, const unsigned char* __restrict__ gb,
        int* __restrict__ bcur, unsigned int* __restrict__ ebuf, int nE) {
    __shared__ unsigned int lw[CHUNK];
    __shared__ unsigned char lg[CHUNK];
    __shared__ int lcnt[256], lbase[256], lcur[256];
    int e0 = blockIdx.x * CHUNK;
    int cnt = nE - e0;
    if (cnt > CHUNK) cnt = CHUNK;
    if (cnt < 0) cnt = 0;
    for (int i = threadIdx.x; i < cnt; i += 256) {
        lw[i] = eword[e0 + i];
        lg[i] = gb[e0 + i];
    }
    lcnt[threadIdx.x] = 0;
    __syncthreads();
    for (int i = threadIdx.x; i < cnt; i += 256)
        atomicAdd(&lcnt[lg[i]], 1);
    __syncthreads();
    int c = lcnt[threadIdx.x];
    if (c > 0) lbase[threadIdx.x] = atomicAdd(&bcur[threadIdx.x], c);
    lcur[threadIdx.x] = 0;
    __syncthreads();
    for (int i = threadIdx.x; i < cnt; i += 256) {
        int g = lg[i];
        int p = lbase[g] + atomicAdd(&lcur[g], 1);
        ebuf[p] = lw[i];
    }
}

__global__ __launch_bounds__(256) void bucket_scatter2(
        const unsigned int* __restrict__ ebuf,
        const int* __restrict__ bstart, const int* __restrict__ bcnt,
        int* __restrict__ offsets, int* __restrict__ csr, int n) {
    __shared__ int ncnt[512], nofs[512], ps[256];
    int g = blockIdx.x;
    int base = bstart[g];
    int cnt = bcnt[g];
    int n0 = g << 9;
    int nr = n - n0; if (nr > 512) nr = 512;
    for (int i = threadIdx.x; i < 512; i += 256) ncnt[i] = 0;
    __syncthreads();
    for (int i = threadIdx.x; i < cnt; i += 256)
        atomicAdd(&ncnt[ebuf[base + i] & 511], 1);
    __syncthreads();
    int t = threadIdx.x;
    int c0 = ncnt[2 * t], c1 = ncnt[2 * t + 1];
    ps[t] = c0 + c1;
    __syncthreads();
    for (int off = 1; off < 256; off <<= 1) {
        int u = 0;
        if (t >= off) u = ps[t - off];
        __syncthreads();
        if (t >= off) ps[t] += u;
        __syncthreads();
    }
    int pex = ps[t] - (c0 + c1);
    nofs[2 * t] = pex;
    nofs[2 * t + 1] = pex + c0;
    __syncthreads();
    for (int i = threadIdx.x; i < nr; i += 256)
        offsets[n0 + i] = base + nofs[i];
    for (int i = threadIdx.x; i < 512; i += 256) ncnt[i] = 0;   // reuse as cursor
    __syncthreads();
    for (int i = threadIdx.x; i < cnt; i += 256) {
        unsigned int w = ebuf[base + i];
        int d = w & 511;
        int p = base + nofs[d] + atomicAdd(&ncnt[d], 1);
        csr[p] = (int)(w >> 9);
    }
}

// ---------------------------------------------------------------------------
// W preprocessing: stacked [Wl;Wr] transposed to [col][k], split bf16 hi/lo.
__global__ void build_wt(const float* __restrict__ Wa, const float* __restrict__ Wr,
                         __bf16* __restrict__ WtHi, __bf16* __restrict__ WtLo) {
    int idx = blockIdx.x * 256 + threadIdx.x;         // 3*128*256 total
    if (idx >= 3 * 128 * 256) return;
    int L = idx / (128 * 256);
    int rem = idx % (128 * 256);
    int c = rem / 256;
    int k = rem % 256;
    float v = (k < 128) ? Wa[((size_t)L * 128 + k) * 128 + c]
                        : Wr[((size_t)L * 128 + (k - 128)) * 128 + c];
    __bf16 h = (__bf16)v;
    __bf16 l = (__bf16)(v - (float)h);
    WtHi[idx] = h;
    WtLo[idx] = l;
}

// ---------------------------------------------------------------------------
// x fp32 -> bf16 plane + fused per-row u8 quant (layer-0 agg input).
__global__ __launch_bounds__(256) void cvt_x_q(
        const float* __restrict__ x, __bf16* __restrict__ a,
        unsigned char* __restrict__ q, float* __restrict__ scl, int total8) {
    int i = blockIdx.x * 256 + threadIdx.x;
    if (i >= total8) return;
    int row = i >> 4;
    int c16 = i & 15;
    const float4* p = (const float4*)(x + (size_t)i * 8);
    float4 v0 = p[0], v1 = p[1];
    float vv[8] = {v0.x, v0.y, v0.z, v0.w, v1.x, v1.y, v1.z, v1.w};
    bf16x8 h;
    float f[8], m = 0.f;
    #pragma unroll
    for (int j = 0; j < 8; ++j) {
        h[j] = (__bf16)vv[j];
        f[j] = (float)h[j];                 // quantize from bf16-rounded value
        m = fmaxf(m, fabsf(f[j]));
    }
    *(bf16x8*)(a + (size_t)i * 8) = h;
    #pragma unroll
    for (int off = 8; off >= 1; off >>= 1)
        m = fmaxf(m, __shfl_xor(m, off));
    float scale = m * (1.0f / 127.0f);
    float inv = (m > 0.f) ? 127.0f / m : 0.f;
    unsigned int pa = 0, pb = 0;
    #pragma unroll
    for (int j = 0; j < 4; ++j)
        pa |= (unsigned int)(__float2int_rn(f[j] * inv) + 128) << (8 * j);
    #pragma unroll
    for (int j = 0; j < 4; ++j)
        pb |= (unsigned int)(__float2int_rn(f[4 + j] * inv) + 128) << (8 * j);
    *(int2*)(q + (size_t)row * D + c16 * 8) = make_int2((int)pa, (int)pb);
    if (c16 == 0) scl[row] = scale;
}

// ---------------------------------------------------------------------------
// mean aggregation v7: gather biased-u8 rows (128B/row) + per-row scale
// (R15/R16-proven structure); output now ALSO u8+scale (halves the mean
// write AND the gemm's mean read). Quant identical to the proven fused path.
__global__ __launch_bounds__(256) void agg_mean7(
        const unsigned char* __restrict__ q, const float* __restrict__ scl,
        const int* __restrict__ csr, const int* __restrict__ offs,
        unsigned char* __restrict__ qm, float* __restrict__ ms, int n) {
    int node = (blockIdx.x * blockDim.x + threadIdx.x) >> 4;
    int l8 = (threadIdx.x & 15) << 3;
    if (node >= n) return;
    int beg = offs[node], end = offs[node + 1];
    float acc[8] = {0.f, 0.f, 0.f, 0.f, 0.f, 0.f, 0.f, 0.f};
    float S = 0.f;
    int i = beg;
    for (; i + 8 <= end; i += 8) {
        int2 v[8]; float s[8];
        #pragma unroll
        for (int u = 0; u < 8; ++u) {
            int src = csr[i + u];
            v[u] = *(const int2*)(q + (size_t)src * D + l8);
            s[u] = scl[src];
        }
        #pragma unroll
        for (int u = 0; u < 8; ++u) {
            unsigned int a = (unsigned int)v[u].x, b = (unsigned int)v[u].y;
            float sv = s[u];
            S += sv;
            acc[0] += (float)(a & 255u) * sv;
            acc[1] += (float)((a >> 8) & 255u) * sv;
            acc[2] += (float)((a >> 16) & 255u) * sv;
            acc[3] += (float)(a >> 24) * sv;
            acc[4] += (float)(b & 255u) * sv;
            acc[5] += (float)((b >> 8) & 255u) * sv;
            acc[6] += (float)((b >> 16) & 255u) * sv;
            acc[7] += (float)(b >> 24) * sv;
        }
    }
    for (; i + 4 <= end; i += 4) {
        int2 v[4]; float s[4];
        #pragma unroll
        for (int u = 0; u < 4; ++u) {
            int src = csr[i + u];
            v[u] = *(const int2*)(q + (size_t)src * D + l8);
            s[u] = scl[src];
        }
        #pragma unroll
        for (int u = 0; u < 4; ++u) {
            unsigned int a = (unsigned int)v[u].x, b = (unsigned int)v[u].y;
            float sv = s[u];
            S += sv;
            acc[0] += (float)(a & 255u) * sv;
            acc[1] += (float)((a >> 8) & 255u) * sv;
            acc[2] += (float)((a >> 16) & 255u) * sv;
            acc[3] += (float)(a >> 24) * sv;
            acc[4] += (float)(b & 255u) * sv;
            acc[5] += (float)((b >> 8) & 255u) * sv;
            acc[6] += (float)((b >> 16) & 255u) * sv;
            acc[7] += (float)(b >> 24) * sv;
        }
    }
    for (; i < end; ++i) {
        int src = csr[i];
        int2 v = *(const int2*)(q + (size_t)src * D + l8);
        float sv = scl[src];
        unsigned int a = (unsigned int)v.x, b = (unsigned int)v.y;
        S += sv;
        acc[0] += (float)(a & 255u) * sv;
        acc[1] += (float)((a >> 8) & 255u) * sv;
        acc[2] += (float)((a >> 16) & 255u) * sv;
        acc[3] += (float)(a >> 24) * sv;
        acc[4] += (float)(b & 255u) * sv;
        acc[5] += (float)((b >> 8) & 255u) * sv;
        acc[6] += (float)((b >> 16) & 255u) * sv;
        acc[7] += (float)(b >> 24) * sv;
    }
    int deg = end - beg;
    float inv = 1.0f / (float)(deg > 1 ? deg : 1);
    float f[8], m = 0.f;
    #pragma unroll
    for (int j = 0; j < 8; ++j) {
        f[j] = (acc[j] - 128.0f * S) * inv;
        m = fmaxf(m, fabsf(f[j]));
    }
    #pragma unroll
    for (int off = 8; off >= 1; off >>= 1)
        m = fmaxf(m, __shfl_xor(m, off));
    float scale = m * (1.0f / 127.0f);
    float qinv = (m > 0.f) ? 127.0f / m : 0.f;
    unsigned int pa = 0, pb = 0;
    #pragma unroll
    for (int j = 0; j < 4; ++j)
        pa |= (unsigned int)(__float2int_rn(f[j] * qinv) + 128) << (8 * j);
    #pragma unroll
    for (int j = 0; j < 4; ++j)
        pb |= (unsigned int)(__float2int_rn(f[4 + j] * qinv) + 128) << (8 * j);
    *(int2*)(qm + (size_t)node * D + l8) = make_int2((int)pa, (int)pb);
    if ((threadIdx.x & 15) == 0) ms[node] = scale;
}

// ---------------------------------------------------------------------------
// MFMA GEMM v8c = R16 gemm8b (swizzled sA + sC, 4 MFMA chains, fused output
// quant) with the MEAN half of the A-tile staged from the u8 qm/ms plane.
// Dequant happens at COMMIT time (post-barrier), not load-issue — raw int2 +
// scale registers ride through the MFMA loop so prefetch latency-hiding is
// preserved (R13 lesson).
__global__ __launch_bounds__(512, 4) void sage_gemm8c(
        const unsigned char* __restrict__ qm, const float* __restrict__ ms,
        const __bf16* __restrict__ act,
        const __bf16* __restrict__ WtHi, const __bf16* __restrict__ WtLo,
        const float* __restrict__ bias,
        __bf16* __restrict__ oB, float* __restrict__ oF,
        unsigned char* __restrict__ qpl, float* __restrict__ scl,
        int n, int mode, int npairs) {
    __shared__ __align__(16) char sA[2][2][8192];  // [buf][half][row:512B, swz]
    __shared__ __align__(16) char sC[2][8192];     // [half] epilogue tile (swz)
    int tid  = threadIdx.x;
    int wave = tid >> 6;
    int lane = tid & 63;
    int r16  = lane & 15;
    int kg   = lane >> 4;
    int colbase = wave * 16;

    bf16x8 BH[8], BL[8];
    #pragma unroll
    for (int c8 = 0; c8 < 8; ++c8) {
        size_t o = (size_t)(colbase + r16) * 256 + c8 * 32 + kg * 8;
        BH[c8] = *(const bf16x8*)(WtHi + o);
        BL[c8] = *(const bf16x8*)(WtLo + o);
    }
    float4 bv = *(const float4*)(bias + colbase + kg * 4);

    int xm = (r16 & 7) << 4;
    int kb[8];
    #pragma unroll
    for (int c8 = 0; c8 < 8; ++c8)
        kb[c8] = r16 * 512 + ((c8 * 64 + kg * 16) ^ xm);

    int srow = tid >> 5;           // 0..15
    int sc16 = tid & 31;           // 0..31 (32 x 16B per row)
    int sdst = srow * 512 + ((sc16 * 16) ^ ((srow & 7) << 4));

    // issue raw loads (no dependent math -> latency can hide under MFMA)
    auto stage_issue = [&](int p, int half, int4& r, float& s) {
        int grow = p * 32 + half * 16 + srow;
        s = 0.f;
        if (grow < n) {
            if (sc16 < 16) {
                int2 v = *(const int2*)(qm + (size_t)grow * D + sc16 * 8);
                r.x = v.x; r.y = v.y; r.z = 0; r.w = 0;
                s = ms[grow];
            } else {
                r = *(const int4*)(act + (size_t)grow * D + (sc16 - 16) * 8);
            }
        } else {
            r = make_int4(0, 0, 0, 0);
        }
    };
    // dequant-or-passthrough at commit time
    auto stage_commit = [&](int4 r, float s) -> int4 {
        if (sc16 < 16) {
            unsigned int a = (unsigned int)r.x, b = (unsigned int)r.y;
            bf16x8 h;
            h[0] = (__bf16)(((float)(a & 255u) - 128.f) * s);
            h[1] = (__bf16)(((float)((a >> 8) & 255u) - 128.f) * s);
            h[2] = (__bf16)(((float)((a >> 16) & 255u) - 128.f) * s);
            h[3] = (__bf16)(((float)(a >> 24) - 128.f) * s);
            h[4] = (__bf16)(((float)(b & 255u) - 128.f) * s);
            h[5] = (__bf16)(((float)((b >> 8) & 255u) - 128.f) * s);
            h[6] = (__bf16)(((float)((b >> 16) & 255u) - 128.f) * s);
            h[7] = (__bf16)(((float)(b >> 24) - 128.f) * s);
            int4 out;
            __builtin_memcpy(&out, &h, 16);
            return out;
        }
        return r;
    };

    int pstride = gridDim.x;
    int p = blockIdx.x;

    {
        int4 r0 = make_int4(0,0,0,0), r1 = make_int4(0,0,0,0);
        float s0 = 0.f, s1 = 0.f;
        if (p < npairs) { stage_issue(p, 0, r0, s0); stage_issue(p, 1, r1, s1); }
        *(int4*)(sA[0][0] + sdst) = stage_commit(r0, s0);
        *(int4*)(sA[0][1] + sdst) = stage_commit(r1, s1);
    }
    __syncthreads();
    int cur = 0;

    for (; p < npairs; p += pstride) {
        int pn = p + pstride;
        bool hasnext = pn < npairs;
        int4 n0, n1; float t0, t1;
        if (hasnext) { stage_issue(pn, 0, n0, t0); stage_issue(pn, 1, n1, t1); }

        // 4 independent MFMA chains over 8 K-chunks
        f32x4 aH0 = (f32x4){0.f,0.f,0.f,0.f}, aL0 = aH0;
        f32x4 aH1 = aH0, aL1 = aH0;
        const char* b0 = sA[cur][0];
        const char* b1 = sA[cur][1];
        #pragma unroll
        for (int c8 = 0; c8 < 8; ++c8) {
            bf16x8 a0 = *(const bf16x8*)(b0 + kb[c8]);
            bf16x8 a1 = *(const bf16x8*)(b1 + kb[c8]);
            aH0 = __builtin_amdgcn_mfma_f32_16x16x32_bf16(BH[c8], a0, aH0, 0, 0, 0);
            aH1 = __builtin_amdgcn_mfma_f32_16x16x32_bf16(BH[c8], a1, aH1, 0, 0, 0);
            aL0 = __builtin_amdgcn_mfma_f32_16x16x32_bf16(BL[c8], a0, aL0, 0, 0, 0);
            aL1 = __builtin_amdgcn_mfma_f32_16x16x32_bf16(BL[c8], a1, aL1, 0, 0, 0);
        }

        __syncthreads();    // sA[cur] reads + previous sC readback done
        if (hasnext) {
            *(int4*)(sA[cur ^ 1][0] + sdst) = stage_commit(n0, t0);
            *(int4*)(sA[cur ^ 1][1] + sdst) = stage_commit(n1, t1);
        }

        // epilogue into sC[half], XOR-swizzled columns
        #pragma unroll
        for (int h = 0; h < 2; ++h) {
            f32x4 a = h ? (aH1 + aL1) : (aH0 + aL0);
            float v0 = a[0] + bv.x;
            float v1 = a[1] + bv.y;
            float v2 = a[2] + bv.z;
            float v3 = a[3] + bv.w;
            if (mode == 0) {
                v0 = fmaxf(v0, 0.f); v1 = fmaxf(v1, 0.f);
                v2 = fmaxf(v2, 0.f); v3 = fmaxf(v3, 0.f);
                bf16x4 h4;
                h4[0] = (__bf16)v0; h4[1] = (__bf16)v1;
                h4[2] = (__bf16)v2; h4[3] = (__bf16)v3;
                *(bf16x4*)(sC[h] + r16 * 256 +
                           (((colbase + kg * 4) * 2) ^ xm)) = h4;
            } else {
                *(f32x4*)(sC[h] + r16 * 512 +
                          (((colbase + kg * 4) * 4) ^ xm)) =
                    (f32x4){v0, v1, v2, v3};
            }
        }
        __syncthreads();

        // cooperative coalesced store of the 32x128 pair (+ fused quant, mode 0)
        if (mode == 0) {
            int rr = tid >> 4, c16 = tid & 15;       // 512 chunks
            int grow = p * 32 + rr;
            int row = rr & 15;
            if (grow < n) {
                int4 hc = *(const int4*)(sC[rr >> 4] + row * 256 +
                                         ((c16 * 16) ^ ((row & 7) << 4)));
                *(int4*)(oB + (size_t)grow * D + c16 * 8) = hc;
                // fused u8 row-quant for the next layer's aggregation
                const unsigned short* hs = (const unsigned short*)&hc;
                float f[8], m = 0.f;
                #pragma unroll
                for (int j = 0; j < 8; ++j) {
                    unsigned int bits = (unsigned int)hs[j] << 16;
                    f[j] = __uint_as_float(bits);
                    m = fmaxf(m, fabsf(f[j]));
                }
                #pragma unroll
                for (int off = 8; off >= 1; off >>= 1)
                    m = fmaxf(m, __shfl_xor(m, off));
                float scale = m * (1.0f / 127.0f);
                float inv = (m > 0.f) ? 127.0f / m : 0.f;
                unsigned int pa = 0, pb = 0;
                #pragma unroll
                for (int j = 0; j < 4; ++j)
                    pa |= (unsigned int)(__float2int_rn(f[j] * inv) + 128) << (8 * j);
                #pragma unroll
                for (int j = 0; j < 4; ++j)
                    pb |= (unsigned int)(__float2int_rn(f[4 + j] * inv) + 128) << (8 * j);
                *(int2*)(qpl + (size_t)grow * D + c16 * 8) =
                    make_int2((int)pa, (int)pb);
                if (c16 == 0) scl[grow] = scale;
            }
        } else {
            #pragma unroll
            for (int pass = 0; pass < 2; ++pass) {
                int chunk = pass * 512 + tid;
                int rr = chunk >> 5, c = chunk & 31;
                int grow = p * 32 + rr;
                int row = rr & 15;
                if (grow < n) {
                    f32x4 f = *(const f32x4*)(sC[rr >> 4] + row * 512 +
                                              ((c * 16) ^ ((row & 7) << 4)));
                    *(f32x4*)(oF + (size_t)grow * D + c * 4) = f;
                }
            }
        }
        cur ^= 1;
    }
}

// ---------------------------------------------------------------------------
extern "C" void kernel_launch(void* const* d_in, const int* in_sizes, int n_in,
                              void* d_out, int out_size, void* d_ws, size_t ws_size,
                              hipStream_t stream) {
    const float* x  = (const float*)d_in[0];
    const void*  ei = d_in[1];
    const float* Wa = (const float*)d_in[2];   // [3,128,128]
    const float* Wr = (const float*)d_in[3];   // [3,128,128]
    const float* bb = (const float*)d_in[4];   // [3,128]
    float* outp = (float*)d_out;

    int n  = in_sizes[0] / D;          // 100000
    int nE = in_sizes[1] / 2;          // 1600000
    int G  = (n + 511) >> 9;           // 512-node buckets (<=256)

    char* ws = (char*)d_ws;
    size_t off = 0;
    auto alloc = [&](size_t bytes) -> char* {
        char* p = ws + off;
        off = (off + bytes + 255) & ~(size_t)255;
        return p;
    };
    int* flag            = (int*)alloc(4);
    unsigned int* eword  = (unsigned int*)alloc((size_t)nE * 4);
    unsigned char* gbuf  = (unsigned char*)alloc((size_t)nE);
    unsigned int* ebuf   = (unsigned int*)alloc((size_t)nE * 4);
    int* offsets         = (int*)alloc(((size_t)n + 1) * 4);
    int* csr_src         = (int*)alloc((size_t)nE * 4);
    int* bcnt            = (int*)alloc(1024);
    int* bstart          = (int*)alloc(1024);
    int* bcur            = (int*)alloc(1024);
    __bf16* actA         = (__bf16*)alloc((size_t)n * D * 2);
    __bf16* actB         = (__bf16*)alloc((size_t)n * D * 2);
    unsigned char* qpl   = (unsigned char*)alloc((size_t)n * D);
    float* scl           = (float*)alloc((size_t)n * 4);
    unsigned char* qm    = (unsigned char*)alloc((size_t)n * D);
    float* ms            = (float*)alloc((size_t)n * 4);
    __bf16* WtHi         = (__bf16*)alloc((size_t)3 * 128 * 256 * 2);
    __bf16* WtLo         = (__bf16*)alloc((size_t)3 * 128 * 256 * 2);
    (void)ws_size; (void)n_in; (void)out_size;

    const int B = 256;

    // 1) probe + fused convert/pack/hist + W transpose/split + x convert+quant
    hipLaunchKernelGGL(detect_idx, dim3(1), dim3(64), 0, stream, ei, flag, n);
    hipMemsetAsync(bcnt, 0, 1024, stream);
    hipLaunchKernelGGL(convert_pack, dim3(512), dim3(B), 0, stream,
                       ei, flag, eword, gbuf, bcnt, nE);
    hipLaunchKernelGGL(build_wt, dim3(384), dim3(256), 0, stream, Wa, Wr, WtHi, WtLo);
    int total8 = n * D / 8;
    hipLaunchKernelGGL(cvt_x_q, dim3((total8 + 255) / 256), dim3(256), 0, stream,
                       x, actA, qpl, scl, total8);

    // 2) bucketed CSR build (packed words)
    hipLaunchKernelGGL(bucket_scan, dim3(1), dim3(B), 0, stream,
                       bcnt, bstart, bcur, G, nE, offsets, n);
    hipLaunchKernelGGL(bucket_fill2, dim3((nE + CHUNK - 1) / CHUNK), dim3(B), 0, stream,
                       eword, gbuf, bcur, ebuf, nE);
    hipLaunchKernelGGL(bucket_scatter2, dim3(G), dim3(B), 0, stream,
                       ebuf, bstart, bcnt, offsets, csr_src, n);

    // 3) layers: agg(u8 -> u8 mean) -> gemm(dequant-stage + fused out-quant)
    int row_blocks = (n * 16 + B - 1) / B;
    int npairs = (n + 31) / 32;
    int gemm_grid = 512;               // R12-measured best
    const int WSTRIDE = 128 * 256;

    // layer 0: actA -> actB (ReLU, bf16 + qpl/scl)
    hipLaunchKernelGGL(agg_mean7, dim3(row_blocks), dim3(B), 0, stream,
                       qpl, scl, csr_src, offsets, qm, ms, n);
    hipLaunchKernelGGL(sage_gemm8c, dim3(gemm_grid), dim3(512), 0, stream,
                       qm, ms, actA, WtHi + 0 * WSTRIDE, WtLo + 0 * WSTRIDE,
                       bb + 0 * D, actB, outp, qpl, scl, n, 0, npairs);

    // layer 1: actB -> actA (ReLU, bf16 + qpl/scl)
    hipLaunchKernelGGL(agg_mean7, dim3(row_blocks), dim3(B), 0, stream,
                       qpl, scl, csr_src, offsets, qm, ms, n);
    hipLaunchKernelGGL(sage_gemm8c, dim3(gemm_grid), dim3(512), 0, stream,
                       qm, ms, actB, WtHi + 1 * WSTRIDE, WtLo + 1 * WSTRIDE,
                       bb + 1 * D, actA, outp, qpl, scl, n, 0, npairs);

    // layer 2: actA -> d_out (no ReLU, fp32)
    hipLaunchKernelGGL(agg_mean7, dim3(row_blocks), dim3(B), 0, stream,
                       qpl, scl, csr_src, offsets, qm, ms, n);
    hipLaunchKernelGGL(sage_gemm8c, dim3(gemm_grid), dim3(512), 0, stream,
                       qm, ms, actA, WtHi + 2 * WSTRIDE, WtLo + 2 * WSTRIDE,
                       bb + 2 * D, actB, outp, qpl, scl, n, 1, npairs);
}

// Round 18
// 296.188 us; speedup vs baseline: 1.0733x; 1.0733x over previous
//
#include <hip/hip_runtime.h>
#include <stdint.h>

#define D 128
#define CHUNK 6400

typedef __attribute__((ext_vector_type(8))) __bf16 bf16x8;
typedef __attribute__((ext_vector_type(4))) __bf16 bf16x4;
typedef __attribute__((ext_vector_type(4))) float f32x4;

// ---------------------------------------------------------------------------
// edge_index dtype detection (int64 per reference vs int32 from x64-disabled JAX)
__global__ void detect_idx(const void* ei, int* flag, int n_nodes) {
    if (blockIdx.x == 0 && threadIdx.x == 0) {
        const long long* p = (const long long*)ei;
        int is64 = 1;
        for (int i = 0; i < 64; ++i) {
            long long v = p[i];
            if (v < 0 || v >= (long long)n_nodes) { is64 = 0; break; }
        }
        *flag = is64;
    }
}

// ---------------------------------------------------------------------------
// one pass over edge_index: packed edge word (src<<9 | dst&511), bucket byte,
// bucket histogram (LDS -> global).
__global__ __launch_bounds__(256) void convert_pack(
        const void* __restrict__ ei, const int* __restrict__ flag,
        unsigned int* __restrict__ eword, unsigned char* __restrict__ gb,
        int* __restrict__ bcnt, int nE) {
    __shared__ int l[256];
    l[threadIdx.x] = 0;
    __syncthreads();
    bool is64 = *flag != 0;
    int stride = gridDim.x * 256;
    for (int e = blockIdx.x * 256 + threadIdx.x; e < nE; e += stride) {
        int s, d;
        if (is64) {
            const long long* p = (const long long*)ei;
            s = (int)p[e];
            d = (int)p[(size_t)nE + e];
        } else {
            const int* p = (const int*)ei;
            s = p[e];
            d = p[nE + e];
        }
        eword[e] = ((unsigned)s << 9) | (unsigned)(d & 511);
        gb[e] = (unsigned char)(d >> 9);
        atomicAdd(&l[d >> 9], 1);
    }
    __syncthreads();
    int v = l[threadIdx.x];
    if (v) atomicAdd(&bcnt[threadIdx.x], v);
}

__global__ void bucket_scan(const int* __restrict__ bcnt, int* __restrict__ bstart,
                            int* __restrict__ bcur, int G, int nE,
                            int* __restrict__ offsets, int n) {
    __shared__ int s[256];
    int t = threadIdx.x;
    int v = (t < G) ? bcnt[t] : 0;
    s[t] = v;
    __syncthreads();
    for (int off = 1; off < 256; off <<= 1) {
        int u = 0;
        if (t >= off) u = s[t - off];
        __syncthreads();
        if (t >= off) s[t] += u;
        __syncthreads();
    }
    if (t < G) { int ex = s[t] - v; bstart[t] = ex; bcur[t] = ex; }
    if (t == 0) offsets[n] = nE;
}

__global__ __launch_bounds__(256) void bucket_fill2(
        const unsigned int* __restrict__ eword, const unsigned char* __restrict__ gb,
        int* __restrict__ bcur, unsigned int* __restrict__ ebuf, int nE) {
    __shared__ unsigned int lw[CHUNK];
    __shared__ unsigned char lg[CHUNK];
    __shared__ int lcnt[256], lbase[256], lcur[256];
    int e0 = blockIdx.x * CHUNK;
    int cnt = nE - e0;
    if (cnt > CHUNK) cnt = CHUNK;
    if (cnt < 0) cnt = 0;
    for (int i = threadIdx.x; i < cnt; i += 256) {
        lw[i] = eword[e0 + i];
        lg[i] = gb[e0 + i];
    }
    lcnt[threadIdx.x] = 0;
    __syncthreads();
    for (int i = threadIdx.x; i < cnt; i += 256)
        atomicAdd(&lcnt[lg[i]], 1);
    __syncthreads();
    int c = lcnt[threadIdx.x];
    if (c > 0) lbase[threadIdx.x] = atomicAdd(&bcur[threadIdx.x], c);
    lcur[threadIdx.x] = 0;
    __syncthreads();
    for (int i = threadIdx.x; i < cnt; i += 256) {
        int g = lg[i];
        int p = lbase[g] + atomicAdd(&lcur[g], 1);
        ebuf[p] = lw[i];
    }
}

__global__ __launch_bounds__(256) void bucket_scatter2(
        const unsigned int* __restrict__ ebuf,
        const int* __restrict__ bstart, const int* __restrict__ bcnt,
        int* __restrict__ offsets, int* __restrict__ csr, int n) {
    __shared__ int ncnt[512], nofs[512], ps[256];
    int g = blockIdx.x;
    int base = bstart[g];
    int cnt = bcnt[g];
    int n0 = g << 9;
    int nr = n - n0; if (nr > 512) nr = 512;
    for (int i = threadIdx.x; i < 512; i += 256) ncnt[i] = 0;
    __syncthreads();
    for (int i = threadIdx.x; i < cnt; i += 256)
        atomicAdd(&ncnt[ebuf[base + i] & 511], 1);
    __syncthreads();
    int t = threadIdx.x;
    int c0 = ncnt[2 * t], c1 = ncnt[2 * t + 1];
    ps[t] = c0 + c1;
    __syncthreads();
    for (int off = 1; off < 256; off <<= 1) {
        int u = 0;
        if (t >= off) u = ps[t - off];
        __syncthreads();
        if (t >= off) ps[t] += u;
        __syncthreads();
    }
    int pex = ps[t] - (c0 + c1);
    nofs[2 * t] = pex;
    nofs[2 * t + 1] = pex + c0;
    __syncthreads();
    for (int i = threadIdx.x; i < nr; i += 256)
        offsets[n0 + i] = base + nofs[i];
    for (int i = threadIdx.x; i < 512; i += 256) ncnt[i] = 0;   // reuse as cursor
    __syncthreads();
    for (int i = threadIdx.x; i < cnt; i += 256) {
        unsigned int w = ebuf[base + i];
        int d = w & 511;
        int p = base + nofs[d] + atomicAdd(&ncnt[d], 1);
        csr[p] = (int)(w >> 9);
    }
}

// ---------------------------------------------------------------------------
// W preprocessing: stacked [Wl;Wr] transposed to [col][k], split bf16 hi/lo.
__global__ void build_wt(const float* __restrict__ Wa, const float* __restrict__ Wr,
                         __bf16* __restrict__ WtHi, __bf16* __restrict__ WtLo) {
    int idx = blockIdx.x * 256 + threadIdx.x;         // 3*128*256 total
    if (idx >= 3 * 128 * 256) return;
    int L = idx / (128 * 256);
    int rem = idx % (128 * 256);
    int c = rem / 256;
    int k = rem % 256;
    float v = (k < 128) ? Wa[((size_t)L * 128 + k) * 128 + c]
                        : Wr[((size_t)L * 128 + (k - 128)) * 128 + c];
    __bf16 h = (__bf16)v;
    __bf16 l = (__bf16)(v - (float)h);
    WtHi[idx] = h;
    WtLo[idx] = l;
}

// ---------------------------------------------------------------------------
// x fp32 -> bf16 plane + fused per-row u8 quant (layer-0 agg input).
// Thread i handles 8 floats; 16 threads per row (aligned within a wave).
__global__ __launch_bounds__(256) void cvt_x_q(
        const float* __restrict__ x, __bf16* __restrict__ a,
        unsigned char* __restrict__ q, float* __restrict__ scl, int total8) {
    int i = blockIdx.x * 256 + threadIdx.x;
    if (i >= total8) return;
    int row = i >> 4;
    int c16 = i & 15;
    const float4* p = (const float4*)(x + (size_t)i * 8);
    float4 v0 = p[0], v1 = p[1];
    float vv[8] = {v0.x, v0.y, v0.z, v0.w, v1.x, v1.y, v1.z, v1.w};
    bf16x8 h;
    float f[8], m = 0.f;
    #pragma unroll
    for (int j = 0; j < 8; ++j) {
        h[j] = (__bf16)vv[j];
        f[j] = (float)h[j];                 // quantize from bf16-rounded value
        m = fmaxf(m, fabsf(f[j]));
    }
    *(bf16x8*)(a + (size_t)i * 8) = h;
    #pragma unroll
    for (int off = 8; off >= 1; off >>= 1)
        m = fmaxf(m, __shfl_xor(m, off));
    float scale = m * (1.0f / 127.0f);
    float inv = (m > 0.f) ? 127.0f / m : 0.f;
    unsigned int pa = 0, pb = 0;
    #pragma unroll
    for (int j = 0; j < 4; ++j)
        pa |= (unsigned int)(__float2int_rn(f[j] * inv) + 128) << (8 * j);
    #pragma unroll
    for (int j = 0; j < 4; ++j)
        pb |= (unsigned int)(__float2int_rn(f[4 + j] * inv) + 128) << (8 * j);
    *(int2*)(q + (size_t)row * D + c16 * 8) = make_int2((int)pa, (int)pb);
    if (c16 == 0) scl[row] = scale;
}

// ---------------------------------------------------------------------------
// mean aggregation v6 (R15/R16-proven): gather biased-u8 rows (128B/row) +
// per-row scale; 16-lane group/node, 8x unrolled gathers, fp32 accum;
// bf16 mean output.
__global__ __launch_bounds__(256) void agg_mean6(
        const unsigned char* __restrict__ q, const float* __restrict__ scl,
        const int* __restrict__ csr, const int* __restrict__ offs,
        __bf16* __restrict__ mean, int n) {
    int node = (blockIdx.x * blockDim.x + threadIdx.x) >> 4;
    int l8 = (threadIdx.x & 15) << 3;
    if (node >= n) return;
    int beg = offs[node], end = offs[node + 1];
    float acc[8] = {0.f, 0.f, 0.f, 0.f, 0.f, 0.f, 0.f, 0.f};
    float S = 0.f;
    int i = beg;
    for (; i + 8 <= end; i += 8) {
        int2 v[8]; float s[8];
        #pragma unroll
        for (int u = 0; u < 8; ++u) {
            int src = csr[i + u];
            v[u] = *(const int2*)(q + (size_t)src * D + l8);
            s[u] = scl[src];
        }
        #pragma unroll
        for (int u = 0; u < 8; ++u) {
            unsigned int a = (unsigned int)v[u].x, b = (unsigned int)v[u].y;
            float sv = s[u];
            S += sv;
            acc[0] += (float)(a & 255u) * sv;
            acc[1] += (float)((a >> 8) & 255u) * sv;
            acc[2] += (float)((a >> 16) & 255u) * sv;
            acc[3] += (float)(a >> 24) * sv;
            acc[4] += (float)(b & 255u) * sv;
            acc[5] += (float)((b >> 8) & 255u) * sv;
            acc[6] += (float)((b >> 16) & 255u) * sv;
            acc[7] += (float)(b >> 24) * sv;
        }
    }
    for (; i + 4 <= end; i += 4) {
        int2 v[4]; float s[4];
        #pragma unroll
        for (int u = 0; u < 4; ++u) {
            int src = csr[i + u];
            v[u] = *(const int2*)(q + (size_t)src * D + l8);
            s[u] = scl[src];
        }
        #pragma unroll
        for (int u = 0; u < 4; ++u) {
            unsigned int a = (unsigned int)v[u].x, b = (unsigned int)v[u].y;
            float sv = s[u];
            S += sv;
            acc[0] += (float)(a & 255u) * sv;
            acc[1] += (float)((a >> 8) & 255u) * sv;
            acc[2] += (float)((a >> 16) & 255u) * sv;
            acc[3] += (float)(a >> 24) * sv;
            acc[4] += (float)(b & 255u) * sv;
            acc[5] += (float)((b >> 8) & 255u) * sv;
            acc[6] += (float)((b >> 16) & 255u) * sv;
            acc[7] += (float)(b >> 24) * sv;
        }
    }
    for (; i < end; ++i) {
        int src = csr[i];
        int2 v = *(const int2*)(q + (size_t)src * D + l8);
        float sv = scl[src];
        unsigned int a = (unsigned int)v.x, b = (unsigned int)v.y;
        S += sv;
        acc[0] += (float)(a & 255u) * sv;
        acc[1] += (float)((a >> 8) & 255u) * sv;
        acc[2] += (float)((a >> 16) & 255u) * sv;
        acc[3] += (float)(a >> 24) * sv;
        acc[4] += (float)(b & 255u) * sv;
        acc[5] += (float)((b >> 8) & 255u) * sv;
        acc[6] += (float)((b >> 16) & 255u) * sv;
        acc[7] += (float)(b >> 24) * sv;
    }
    int deg = end - beg;
    float inv = 1.0f / (float)(deg > 1 ? deg : 1);
    bf16x8 h;
    #pragma unroll
    for (int j = 0; j < 8; ++j)
        h[j] = (__bf16)((acc[j] - 128.0f * S) * inv);
    *(bf16x8*)(mean + (size_t)node * D + l8) = h;
}

// ---------------------------------------------------------------------------
// MFMA GEMM v8b (R16-proven): swizzled sA + swizzled sC epilogue (same
// involution byte^=(row&7)<<4 on both sides), 4 independent MFMA chains over
// a 32-row pair, W frags in VGPR, fused u8 row-quant in the mode-0 store.
__global__ __launch_bounds__(512, 4) void sage_gemm8b(
        const __bf16* __restrict__ mean, const __bf16* __restrict__ act,
        const __bf16* __restrict__ WtHi, const __bf16* __restrict__ WtLo,
        const float* __restrict__ bias,
        __bf16* __restrict__ oB, float* __restrict__ oF,
        unsigned char* __restrict__ qpl, float* __restrict__ scl,
        int n, int mode, int npairs) {
    __shared__ __align__(16) char sA[2][2][8192];  // [buf][half][row:512B, swz]
    __shared__ __align__(16) char sC[2][8192];     // [half] epilogue tile (swz)
    int tid  = threadIdx.x;
    int wave = tid >> 6;
    int lane = tid & 63;
    int r16  = lane & 15;
    int kg   = lane >> 4;
    int colbase = wave * 16;

    bf16x8 BH[8], BL[8];
    #pragma unroll
    for (int c8 = 0; c8 < 8; ++c8) {
        size_t o = (size_t)(colbase + r16) * 256 + c8 * 32 + kg * 8;
        BH[c8] = *(const bf16x8*)(WtHi + o);
        BL[c8] = *(const bf16x8*)(WtLo + o);
    }
    float4 bv = *(const float4*)(bias + colbase + kg * 4);

    int xm = (r16 & 7) << 4;
    int kb[8];
    #pragma unroll
    for (int c8 = 0; c8 < 8; ++c8)
        kb[c8] = r16 * 512 + ((c8 * 64 + kg * 16) ^ xm);

    int srow = tid >> 5;           // 0..15
    int sc16 = tid & 31;           // 0..31 (32 x 16B per row)
    int sdst = srow * 512 + ((sc16 * 16) ^ ((srow & 7) << 4));

    auto stage_load = [&](int p, int half, int4& r) {
        int grow = p * 32 + half * 16 + srow;
        if (grow < n) {
            const __bf16* src = (sc16 < 16)
                ? (mean + (size_t)grow * D + sc16 * 8)
                : (act  + (size_t)grow * D + (sc16 - 16) * 8);
            r = *(const int4*)src;
        } else {
            r = make_int4(0, 0, 0, 0);
        }
    };

    int pstride = gridDim.x;
    int p = blockIdx.x;

    {
        int4 r0 = make_int4(0,0,0,0), r1 = make_int4(0,0,0,0);
        if (p < npairs) { stage_load(p, 0, r0); stage_load(p, 1, r1); }
        *(int4*)(sA[0][0] + sdst) = r0;
        *(int4*)(sA[0][1] + sdst) = r1;
    }
    __syncthreads();
    int cur = 0;

    for (; p < npairs; p += pstride) {
        int pn = p + pstride;
        bool hasnext = pn < npairs;
        int4 n0, n1;
        if (hasnext) { stage_load(pn, 0, n0); stage_load(pn, 1, n1); }

        // 4 independent MFMA chains over 8 K-chunks
        f32x4 aH0 = (f32x4){0.f,0.f,0.f,0.f}, aL0 = aH0;
        f32x4 aH1 = aH0, aL1 = aH0;
        const char* b0 = sA[cur][0];
        const char* b1 = sA[cur][1];
        #pragma unroll
        for (int c8 = 0; c8 < 8; ++c8) {
            bf16x8 a0 = *(const bf16x8*)(b0 + kb[c8]);
            bf16x8 a1 = *(const bf16x8*)(b1 + kb[c8]);
            aH0 = __builtin_amdgcn_mfma_f32_16x16x32_bf16(BH[c8], a0, aH0, 0, 0, 0);
            aH1 = __builtin_amdgcn_mfma_f32_16x16x32_bf16(BH[c8], a1, aH1, 0, 0, 0);
            aL0 = __builtin_amdgcn_mfma_f32_16x16x32_bf16(BL[c8], a0, aL0, 0, 0, 0);
            aL1 = __builtin_amdgcn_mfma_f32_16x16x32_bf16(BL[c8], a1, aL1, 0, 0, 0);
        }

        __syncthreads();    // sA[cur] reads + previous sC readback done
        if (hasnext) {
            *(int4*)(sA[cur ^ 1][0] + sdst) = n0;
            *(int4*)(sA[cur ^ 1][1] + sdst) = n1;
        }

        // epilogue into sC[half], XOR-swizzled columns
        #pragma unroll
        for (int h = 0; h < 2; ++h) {
            f32x4 a = h ? (aH1 + aL1) : (aH0 + aL0);
            float v0 = a[0] + bv.x;
            float v1 = a[1] + bv.y;
            float v2 = a[2] + bv.z;
            float v3 = a[3] + bv.w;
            if (mode == 0) {
                v0 = fmaxf(v0, 0.f); v1 = fmaxf(v1, 0.f);
                v2 = fmaxf(v2, 0.f); v3 = fmaxf(v3, 0.f);
                bf16x4 h4;
                h4[0] = (__bf16)v0; h4[1] = (__bf16)v1;
                h4[2] = (__bf16)v2; h4[3] = (__bf16)v3;
                *(bf16x4*)(sC[h] + r16 * 256 +
                           (((colbase + kg * 4) * 2) ^ xm)) = h4;
            } else {
                *(f32x4*)(sC[h] + r16 * 512 +
                          (((colbase + kg * 4) * 4) ^ xm)) =
                    (f32x4){v0, v1, v2, v3};
            }
        }
        __syncthreads();

        // cooperative coalesced store of the 32x128 pair (+ fused quant, mode 0)
        if (mode == 0) {
            int rr = tid >> 4, c16 = tid & 15;       // 512 chunks
            int grow = p * 32 + rr;
            int row = rr & 15;
            if (grow < n) {
                int4 hc = *(const int4*)(sC[rr >> 4] + row * 256 +
                                         ((c16 * 16) ^ ((row & 7) << 4)));
                *(int4*)(oB + (size_t)grow * D + c16 * 8) = hc;
                // fused u8 row-quant for the next layer's aggregation
                const unsigned short* hs = (const unsigned short*)&hc;
                float f[8], m = 0.f;
                #pragma unroll
                for (int j = 0; j < 8; ++j) {
                    unsigned int bits = (unsigned int)hs[j] << 16;
                    f[j] = __uint_as_float(bits);
                    m = fmaxf(m, fabsf(f[j]));
                }
                #pragma unroll
                for (int off = 8; off >= 1; off >>= 1)
                    m = fmaxf(m, __shfl_xor(m, off));
                float scale = m * (1.0f / 127.0f);
                float inv = (m > 0.f) ? 127.0f / m : 0.f;
                unsigned int pa = 0, pb = 0;
                #pragma unroll
                for (int j = 0; j < 4; ++j)
                    pa |= (unsigned int)(__float2int_rn(f[j] * inv) + 128) << (8 * j);
                #pragma unroll
                for (int j = 0; j < 4; ++j)
                    pb |= (unsigned int)(__float2int_rn(f[4 + j] * inv) + 128) << (8 * j);
                *(int2*)(qpl + (size_t)grow * D + c16 * 8) =
                    make_int2((int)pa, (int)pb);
                if (c16 == 0) scl[grow] = scale;
            }
        } else {
            #pragma unroll
            for (int pass = 0; pass < 2; ++pass) {
                int chunk = pass * 512 + tid;
                int rr = chunk >> 5, c = chunk & 31;
                int grow = p * 32 + rr;
                int row = rr & 15;
                if (grow < n) {
                    f32x4 f = *(const f32x4*)(sC[rr >> 4] + row * 512 +
                                              ((c * 16) ^ ((row & 7) << 4)));
                    *(f32x4*)(oF + (size_t)grow * D + c * 4) = f;
                }
            }
        }
        cur ^= 1;
    }
}

// ---------------------------------------------------------------------------
extern "C" void kernel_launch(void* const* d_in, const int* in_sizes, int n_in,
                              void* d_out, int out_size, void* d_ws, size_t ws_size,
                              hipStream_t stream) {
    const float* x  = (const float*)d_in[0];
    const void*  ei = d_in[1];
    const float* Wa = (const float*)d_in[2];   // [3,128,128]
    const float* Wr = (const float*)d_in[3];   // [3,128,128]
    const float* bb = (const float*)d_in[4];   // [3,128]
    float* outp = (float*)d_out;

    int n  = in_sizes[0] / D;          // 100000
    int nE = in_sizes[1] / 2;          // 1600000
    int G  = (n + 511) >> 9;           // 512-node buckets (<=256)

    char* ws = (char*)d_ws;
    size_t off = 0;
    auto alloc = [&](size_t bytes) -> char* {
        char* p = ws + off;
        off = (off + bytes + 255) & ~(size_t)255;
        return p;
    };
    int* flag            = (int*)alloc(4);
    unsigned int* eword  = (unsigned int*)alloc((size_t)nE * 4);
    unsigned char* gbuf  = (unsigned char*)alloc((size_t)nE);
    unsigned int* ebuf   = (unsigned int*)alloc((size_t)nE * 4);
    int* offsets         = (int*)alloc(((size_t)n + 1) * 4);
    int* csr_src         = (int*)alloc((size_t)nE * 4);
    int* bcnt            = (int*)alloc(1024);
    int* bstart          = (int*)alloc(1024);
    int* bcur            = (int*)alloc(1024);
    __bf16* actA         = (__bf16*)alloc((size_t)n * D * 2);
    __bf16* actB         = (__bf16*)alloc((size_t)n * D * 2);
    __bf16* meanP        = (__bf16*)alloc((size_t)n * D * 2);
    unsigned char* qpl   = (unsigned char*)alloc((size_t)n * D);
    float* scl           = (float*)alloc((size_t)n * 4);
    __bf16* WtHi         = (__bf16*)alloc((size_t)3 * 128 * 256 * 2);
    __bf16* WtLo         = (__bf16*)alloc((size_t)3 * 128 * 256 * 2);
    (void)ws_size; (void)n_in; (void)out_size;

    const int B = 256;

    // 1) probe + fused convert/pack/hist + W transpose/split + x convert+quant
    hipLaunchKernelGGL(detect_idx, dim3(1), dim3(64), 0, stream, ei, flag, n);
    hipMemsetAsync(bcnt, 0, 1024, stream);
    hipLaunchKernelGGL(convert_pack, dim3(512), dim3(B), 0, stream,
                       ei, flag, eword, gbuf, bcnt, nE);
    hipLaunchKernelGGL(build_wt, dim3(384), dim3(256), 0, stream, Wa, Wr, WtHi, WtLo);
    int total8 = n * D / 8;
    hipLaunchKernelGGL(cvt_x_q, dim3((total8 + 255) / 256), dim3(256), 0, stream,
                       x, actA, qpl, scl, total8);

    // 2) bucketed CSR build (packed words)
    hipLaunchKernelGGL(bucket_scan, dim3(1), dim3(B), 0, stream,
                       bcnt, bstart, bcur, G, nE, offsets, n);
    hipLaunchKernelGGL(bucket_fill2, dim3((nE + CHUNK - 1) / CHUNK), dim3(B), 0, stream,
                       eword, gbuf, bcur, ebuf, nE);
    hipLaunchKernelGGL(bucket_scatter2, dim3(G), dim3(B), 0, stream,
                       ebuf, bstart, bcnt, offsets, csr_src, n);

    // 3) layers: agg(u8) -> gemm(+fused quant of its output)
    int row_blocks = (n * 16 + B - 1) / B;
    int npairs = (n + 31) / 32;
    int gemm_grid = 512;               // R12-measured best
    const int WSTRIDE = 128 * 256;

    // layer 0: actA -> actB (ReLU, bf16 + qpl/scl)
    hipLaunchKernelGGL(agg_mean6, dim3(row_blocks), dim3(B), 0, stream,
                       qpl, scl, csr_src, offsets, meanP, n);
    hipLaunchKernelGGL(sage_gemm8b, dim3(gemm_grid), dim3(512), 0, stream,
                       meanP, actA, WtHi + 0 * WSTRIDE, WtLo + 0 * WSTRIDE,
                       bb + 0 * D, actB, outp, qpl, scl, n, 0, npairs);

    // layer 1: actB -> actA (ReLU, bf16 + qpl/scl)
    hipLaunchKernelGGL(agg_mean6, dim3(row_blocks), dim3(B), 0, stream,
                       qpl, scl, csr_src, offsets, meanP, n);
    hipLaunchKernelGGL(sage_gemm8b, dim3(gemm_grid), dim3(512), 0, stream,
                       meanP, actB, WtHi + 1 * WSTRIDE, WtLo + 1 * WSTRIDE,
                       bb + 1 * D, actA, outp, qpl, scl, n, 0, npairs);

    // layer 2: actA -> d_out (no ReLU, fp32)
    hipLaunchKernelGGL(agg_mean6, dim3(row_blocks), dim3(B), 0, stream,
                       qpl, scl, csr_src, offsets, meanP, n);
    hipLaunchKernelGGL(sage_gemm8b, dim3(gemm_grid), dim3(512), 0, stream,
                       meanP, actA, WtHi + 2 * WSTRIDE, WtLo + 2 * WSTRIDE,
                       bb + 2 * D, actB, outp, qpl, scl, n, 1, npairs);
}